// Round 1
// baseline (3995.221 us; speedup 1.0000x reference)
//
#include <hip/hip_runtime.h>
#include <hip/hip_bf16.h>

// MsaHmmCell forward scan, MI355X persistent-cluster design.
// M=2 models, B=64 batch, T=512 steps, D=26 obs dim, q=515 states.
// out[t,m,b,q] = log(u_t) + ll_{t-1}, u_t = E_t*(u_{t-1}@A)/S_{t-1}.
// 16 clusters (m x b-group-of-8) x 9 wgs (64-col slice of A each).

#define Tt 512
#define Mm 2
#define Bb 64
#define Dd 26
#define Qq 515
#define QP 576   // padded q (9 x 64 col chunks)
#define KP 544   // padded K (17 x 32)
#define AST 552  // LDS row stride (elements) for A / alpha: %8==0, bank-friendly
#define BCH 8    // b rows per cluster
#define NCL 16   // clusters = Mm * (Bb/BCH)
#define NW 9     // wgs per cluster
#define NBLK 144 // NCL * NW

typedef __attribute__((ext_vector_type(4))) float f32x4;
typedef __attribute__((ext_vector_type(8))) short short8;

__device__ __forceinline__ short f2bf(float f) {
  union { float f; unsigned u; } v; v.f = f;
  unsigned r = v.u + 0x7FFFu + ((v.u >> 16) & 1u);  // RNE
  return (short)(r >> 16);
}

// ---------------- prep kernels ----------------

// obs f32 [M][B][T][26] -> bf16 [M][B][T][32] (d padded with 0)
__global__ void prep_obs_k(const float* __restrict__ obs, short* __restrict__ obsb) {
  int o = blockIdx.x * 256 + threadIdx.x;  // < Mm*Bb*Tt*32
  int d = o & 31; int r = o >> 5;
  float v = (d < Dd) ? obs[r * Dd + d] : 0.f;
  obsb[o] = f2bf(v);
}

// softmax rows of A_logits -> bf16 chunks Ach[m][j][k<544][cc<64] (zeros padded)
__global__ void prep_A_k(const float* __restrict__ Alog, short* __restrict__ Ach) {
  __shared__ float srow[Qq];
  __shared__ float sred[8];
  int m = blockIdx.x / KP, k = blockIdx.x % KP;
  int tid = threadIdx.x; int lane = tid & 63; int w = tid >> 6;
  if (k < Qq) {
    const float* rp = Alog + (m * Qq + k) * Qq;
    for (int i = tid; i < Qq; i += 256) srow[i] = rp[i];
    __syncthreads();
    float lm = -3.4e38f;
    for (int i = tid; i < Qq; i += 256) lm = fmaxf(lm, srow[i]);
    for (int o = 32; o; o >>= 1) lm = fmaxf(lm, __shfl_xor(lm, o, 64));
    if (lane == 0) sred[w] = lm;
    __syncthreads();
    float mx = fmaxf(fmaxf(sred[0], sred[1]), fmaxf(sred[2], sred[3]));
    float ls = 0.f;
    for (int i = tid; i < Qq; i += 256) ls += __expf(srow[i] - mx);
    for (int o = 32; o; o >>= 1) ls += __shfl_xor(ls, o, 64);
    if (lane == 0) sred[4 + w] = ls;
    __syncthreads();
    float rz = 1.f / (sred[4] + sred[5] + sred[6] + sred[7]);
    for (int p = tid; p < QP; p += 256) {
      float v = (p < Qq) ? __expf(srow[p] - mx) * rz : 0.f;
      Ach[((m * NW + (p >> 6)) * KP + k) * 64 + (p & 63)] = f2bf(v);
    }
  } else {
    for (int p = tid; p < QP; p += 256)
      Ach[((m * NW + (p >> 6)) * KP + k) * 64 + (p & 63)] = 0;
  }
}

// softmax rows of B_logits -> bf16 BmT[m][j][cc<64][d<32] (zeros padded)
__global__ void prep_BmT_k(const float* __restrict__ Blog, short* __restrict__ BmT) {
  int m = blockIdx.x / QP, q = blockIdx.x % QP;
  int lane = threadIdx.x;  // block of 64
  bool act = (q < Qq) && (lane < Dd);
  float x = act ? Blog[(m * Qq + q) * Dd + lane] : -3.4e38f;
  float mm = x;
  for (int o = 32; o; o >>= 1) mm = fmaxf(mm, __shfl_xor(mm, o, 64));
  float e = act ? __expf(x - mm) : 0.f;
  float s = e;
  for (int o = 32; o; o >>= 1) s += __shfl_xor(s, o, 64);
  if (lane < 32) {
    float v = act ? (e / s) : 0.f;
    BmT[((m * NW + (q >> 6)) * 64 + (q & 63)) * 32 + lane] = f2bf(v);
  }
}

// softmax init_logits -> pi f32 [M][576] (zeros padded)
__global__ void prep_pi_k(const float* __restrict__ Ilog, float* __restrict__ pi) {
  __shared__ float srow[Qq];
  __shared__ float sred[8];
  int m = blockIdx.x;
  int tid = threadIdx.x; int lane = tid & 63; int w = tid >> 6;
  const float* rp = Ilog + m * Qq;
  for (int i = tid; i < Qq; i += 256) srow[i] = rp[i];
  __syncthreads();
  float lm = -3.4e38f;
  for (int i = tid; i < Qq; i += 256) lm = fmaxf(lm, srow[i]);
  for (int o = 32; o; o >>= 1) lm = fmaxf(lm, __shfl_xor(lm, o, 64));
  if (lane == 0) sred[w] = lm;
  __syncthreads();
  float mx = fmaxf(fmaxf(sred[0], sred[1]), fmaxf(sred[2], sred[3]));
  float ls = 0.f;
  for (int i = tid; i < Qq; i += 256) ls += __expf(srow[i] - mx);
  for (int o = 32; o; o >>= 1) ls += __shfl_xor(ls, o, 64);
  if (lane == 0) sred[4 + w] = ls;
  __syncthreads();
  float rz = 1.f / (sred[4] + sred[5] + sred[6] + sred[7]);
  for (int p = tid; p < QP; p += 256)
    pi[m * QP + p] = (p < Qq) ? __expf(srow[p] - mx) * rz : 0.f;
}

// ---------------- persistent scan kernel ----------------

__global__ void __launch_bounds__(256, 1) scan_k(
    const short* __restrict__ Ach, const short* __restrict__ obsb,
    const short* __restrict__ BmT, const float* __restrict__ pi,
    float* u, float* ps, unsigned int* bar, float* __restrict__ out) {
  extern __shared__ char lds[];
  short* Alds = (short*)lds;                          // [64][AST] A slice, transposed
  short* alds = (short*)(lds + 64 * AST * 2);         // [16][AST] alpha (rows 8..15 zero)
  short* blds = (short*)(lds + 80 * AST * 2);         // [64][32]  Bm^T slice
  float* sS   = (float*)(lds + 80 * AST * 2 + 4096);  // [8] row sums S
  float* red  = (float*)(lds + 80 * AST * 2 + 4096 + 32);  // [4][8] wave row partials

  const int blk = blockIdx.x;
  const int c = blk & (NCL - 1);  // cluster; members of a cluster are == mod 16 -> same XCD (mod 8)
  const int j = blk >> 4;         // col-chunk 0..8
  const int m = c >> 3, bg = c & 7, b0 = bg * BCH;
  const int q0 = j * 64;
  const int tid = threadIdx.x, lane = tid & 63, w = tid >> 6;
  const int col = lane & 15, g = lane >> 4;
  const int qw = q0 + w * 16;
  const int qg = qw + col;

  // one-time: A slice -> LDS transposed [cc][k]
  for (int i = tid; i < KP * 64; i += 256) {
    int k = i >> 6, cc = i & 63;
    Alds[cc * AST + k] = Ach[((m * NW + j) * KP + k) * 64 + cc];
  }
  for (int i = tid; i < 64 * 32; i += 256) blds[i] = BmT[(m * NW + j) * 2048 + i];
  for (int i = tid; i < 8 * AST; i += 256) alds[8 * AST + i] = 0;  // zero pad rows
  __syncthreads();

  unsigned int* barp = bar + c * 16;
  float* ub0 = u + c * (BCH * QP);
  float* ub1 = u + (NCL + c) * (BCH * QP);

  int brow = b0 + col; if (brow > Bb - 1) brow = Bb - 1;  // clamp (rows 8..15 unused)
  const short* obsp = obsb + ((size_t)(m * Bb + brow) * Tt) * 32 + g * 8;

  const f32x4 zf = {0.f, 0.f, 0.f, 0.f};
  float LL[4] = {0.f, 0.f, 0.f, 0.f};

  short8 bmF = *(const short8*)(blds + (w * 16 + col) * 32 + g * 8);

  // ---- t = 0 : u0 = E0 * pi ----
  {
    short8 obsF = *(const short8*)(obsp);
    f32x4 eacc = __builtin_amdgcn_mfma_f32_16x16x32_bf16(obsF, bmF, zf, 0, 0, 0);
    float piv = pi[m * QP + qg];
    float uv[4];
#pragma unroll
    for (int i = 0; i < 4; ++i) {
      int r = g * 4 + i;
      float val = (r < BCH) ? eacc[i] * piv : 0.f;
      uv[i] = val;
      if (r < BCH) {
        if (qg < Qq) out[((size_t)m * Bb + b0 + r) * Qq + qg] = __logf(val);
        __hip_atomic_store(ub0 + r * QP + qg, val, __ATOMIC_RELAXED, __HIP_MEMORY_SCOPE_AGENT);
      }
    }
#pragma unroll
    for (int i = 0; i < 4; ++i) {
      float v = uv[i];
      v += __shfl_xor(v, 1, 64); v += __shfl_xor(v, 2, 64);
      v += __shfl_xor(v, 4, 64); v += __shfl_xor(v, 8, 64);
      if (col == 0 && (g * 4 + i) < BCH) red[w * 8 + g * 4 + i] = v;
    }
    __syncthreads();
    if (tid < BCH) {
      float s = red[tid] + red[8 + tid] + red[16 + tid] + red[24 + tid];
      __hip_atomic_store(ps + ((0 * NCL + c) * NW + j) * 8 + tid, s, __ATOMIC_RELAXED, __HIP_MEMORY_SCOPE_AGENT);
    }
    __syncthreads();  // drains all stores before arrive
    if (tid == 0) {
      __hip_atomic_fetch_add(barp, 1u, __ATOMIC_RELEASE, __HIP_MEMORY_SCOPE_AGENT);
      while (__hip_atomic_load(barp, __ATOMIC_ACQUIRE, __HIP_MEMORY_SCOPE_AGENT) < (unsigned)NW) {}
    }
    __syncthreads();
  }

  // ---- t = 1 .. 511 ----
  for (int t = 1; t < Tt; ++t) {
    const int pp = (t - 1) & 1, p = t & 1;
    float* ubr = pp ? ub1 : ub0;
    float* ubw = p ? ub1 : ub0;

    short8 obsF = *(const short8*)(obsp + t * 32);  // prefetch early

    if (tid < BCH) {  // gather S rows from 9 partials
      float s = 0.f;
      for (int jj = 0; jj < NW; ++jj)
        s += __hip_atomic_load(ps + ((pp * NCL + c) * NW + jj) * 8 + tid, __ATOMIC_RELAXED, __HIP_MEMORY_SCOPE_AGENT);
      sS[tid] = s;
    }
    // stage u_{t-1} (rows 0..7, k<544) -> alds as bf16 pairs
    for (int i = tid; i < BCH * (KP / 2); i += 256) {
      int r = i / (KP / 2), kp = i % (KP / 2);
      unsigned long long two = __hip_atomic_load(
          (const unsigned long long*)(ubr + r * QP + 2 * kp), __ATOMIC_RELAXED, __HIP_MEMORY_SCOPE_AGENT);
      union { unsigned long long q; float f[2]; } cv; cv.q = two;
      unsigned int pk = (unsigned int)(unsigned short)f2bf(cv.f[0]) |
                        ((unsigned int)(unsigned short)f2bf(cv.f[1]) << 16);
      *(unsigned int*)(alds + r * AST + 2 * kp) = pk;
    }
    __syncthreads();

    float rcp[4];
#pragma unroll
    for (int i = 0; i < 4; ++i) {
      int r = g * 4 + i;
      if (r < BCH) { float s = sS[r]; rcp[i] = 1.f / s; LL[i] += __logf(s); }
      else rcp[i] = 0.f;
    }

    // R = alpha @ A_slice  (16 x 544 @ 544 x 16-per-wave)
    f32x4 acc = zf;
    const short* arow = alds + col * AST;
    const short* brow2 = Alds + (w * 16 + col) * AST;
#pragma unroll
    for (int kk = 0; kk < KP / 32; ++kk) {
      short8 aF = *(const short8*)(arow + kk * 32 + g * 8);
      short8 bF = *(const short8*)(brow2 + kk * 32 + g * 8);
      acc = __builtin_amdgcn_mfma_f32_16x16x32_bf16(aF, bF, acc, 0, 0, 0);
    }
    // E_t slice = obs_t @ Bm^T  (one MFMA)
    f32x4 eacc = __builtin_amdgcn_mfma_f32_16x16x32_bf16(obsF, bmF, zf, 0, 0, 0);

    float uv[4];
#pragma unroll
    for (int i = 0; i < 4; ++i) {
      int r = g * 4 + i;
      float val = (r < BCH) ? eacc[i] * acc[i] * rcp[i] : 0.f;
      uv[i] = val;
      if (r < BCH) {
        if (qg < Qq) out[(((size_t)t * Mm + m) * Bb + b0 + r) * Qq + qg] = __logf(val) + LL[i];
        __hip_atomic_store(ubw + r * QP + qg, val, __ATOMIC_RELAXED, __HIP_MEMORY_SCOPE_AGENT);
      }
    }
#pragma unroll
    for (int i = 0; i < 4; ++i) {  // row sums over this wg's 64 cols
      float v = uv[i];
      v += __shfl_xor(v, 1, 64); v += __shfl_xor(v, 2, 64);
      v += __shfl_xor(v, 4, 64); v += __shfl_xor(v, 8, 64);
      if (col == 0 && (g * 4 + i) < BCH) red[w * 8 + g * 4 + i] = v;
    }
    __syncthreads();
    if (tid < BCH) {
      float s = red[tid] + red[8 + tid] + red[16 + tid] + red[24 + tid];
      __hip_atomic_store(ps + ((p * NCL + c) * NW + j) * 8 + tid, s, __ATOMIC_RELAXED, __HIP_MEMORY_SCOPE_AGENT);
    }
    if (t < Tt - 1) {
      __syncthreads();  // drains all stores before arrive
      if (tid == 0) {
        __hip_atomic_fetch_add(barp, 1u, __ATOMIC_RELEASE, __HIP_MEMORY_SCOPE_AGENT);
        unsigned tgt = (unsigned)(NW * (t + 1));
        while (__hip_atomic_load(barp, __ATOMIC_ACQUIRE, __HIP_MEMORY_SCOPE_AGENT) < tgt) {}
      }
      __syncthreads();
    }
  }
}

// ---------------- launch ----------------

extern "C" void kernel_launch(void* const* d_in, const int* in_sizes, int n_in,
                              void* d_out, int out_size, void* d_ws, size_t ws_size,
                              hipStream_t stream) {
  const float* obs  = (const float*)d_in[0];
  const float* Alog = (const float*)d_in[1];
  const float* Blog = (const float*)d_in[2];
  const float* Ilog = (const float*)d_in[3];
  float* out = (float*)d_out;
  char* ws = (char*)d_ws;

  // workspace layout (bytes)
  short*    Ach  = (short*)(ws + 0);          // 2*9*544*64*2       = 1,253,376
  short*    obsb = (short*)(ws + 1253376);    // 2*64*512*32*2      = 4,194,304
  short*    BmT  = (short*)(ws + 5447680);    // 2*9*64*32*2        = 73,728
  float*    pi   = (float*)(ws + 5521408);    // 2*576*4            = 4,608
  float*    u    = (float*)(ws + 5526016);    // 2*16*8*576*4       = 589,824
  float*    ps   = (float*)(ws + 6115840);    // 2*16*9*8*4         = 9,216
  unsigned* bar  = (unsigned*)(ws + 6125056); // 16*16*4            = 1,024
  if (ws_size < 6130000) return;

  hipMemsetAsync(bar, 0, 1024, stream);
  prep_obs_k<<<(Mm * Bb * Tt * 32) / 256, 256, 0, stream>>>(obs, obsb);
  prep_A_k<<<Mm * KP, 256, 0, stream>>>(Alog, Ach);
  prep_BmT_k<<<Mm * QP, 64, 0, stream>>>(Blog, BmT);
  prep_pi_k<<<Mm, 256, 0, stream>>>(Ilog, pi);

  const int ldsBytes = 80 * AST * 2 + 4096 + 32 + 128;  // 92,576
  hipFuncSetAttribute((const void*)scan_k, hipFuncAttributeMaxDynamicSharedMemorySize, ldsBytes);
  scan_k<<<NBLK, 256, ldsBytes, stream>>>(Ach, obsb, BmT, pi, u, ps, bar, out);
}

// Round 2
// 3718.198 us; speedup vs baseline: 1.0745x; 1.0745x over previous
//
#include <hip/hip_runtime.h>
#include <hip/hip_bf16.h>

// MsaHmmCell forward scan, MI355X producer-consumer flag design (R2).
// M=2, B=64, T=512, D=26, q=515. out[t,m,b,q] = log(u_t) + ll_{t-1}.
// 8 clusters (m x b-group-of-16) x 9 wgs (64-col slice of A each) = 72 wgs.
// Sync: per-wg monotonic flag (RELEASE after drain), consumers poll; no barrier.

#define Tt 512
#define Mm 2
#define Bb 64
#define Dd 26
#define Qq 515
#define QP 576   // padded q (9 x 64 col chunks)
#define KP 544   // padded K (17 x 32)
#define AST 568  // LDS row stride (elems): 1136 B = 71 x 16B slots -> 2-way max on b128 reads
#define BCH 16   // b rows per cluster (full MFMA row dim)
#define NCL 8    // clusters = Mm * (Bb/BCH)
#define NW 9     // wgs per cluster
#define NBLK 72

typedef __attribute__((ext_vector_type(4))) float f32x4;
typedef __attribute__((ext_vector_type(8))) short short8;

__device__ __forceinline__ short f2bf(float f) {
  union { float f; unsigned u; } v; v.f = f;
  unsigned r = v.u + 0x7FFFu + ((v.u >> 16) & 1u);  // RNE
  return (short)(r >> 16);
}

// ---------------- prep kernels ----------------

// obs f32 [M][B][T][26] -> bf16 [M][B][T][32] (d padded with 0)
__global__ void prep_obs_k(const float* __restrict__ obs, short* __restrict__ obsb) {
  int o = blockIdx.x * 256 + threadIdx.x;
  int d = o & 31; int r = o >> 5;
  float v = (d < Dd) ? obs[r * Dd + d] : 0.f;
  obsb[o] = f2bf(v);
}

// softmax rows of A_logits -> bf16 chunks Ach[m][j][k<544][cc<64] (zeros padded)
__global__ void prep_A_k(const float* __restrict__ Alog, short* __restrict__ Ach) {
  __shared__ float srow[Qq];
  __shared__ float sred[8];
  int m = blockIdx.x / KP, k = blockIdx.x % KP;
  int tid = threadIdx.x; int lane = tid & 63; int w = tid >> 6;
  if (k < Qq) {
    const float* rp = Alog + (m * Qq + k) * Qq;
    for (int i = tid; i < Qq; i += 256) srow[i] = rp[i];
    __syncthreads();
    float lm = -3.4e38f;
    for (int i = tid; i < Qq; i += 256) lm = fmaxf(lm, srow[i]);
    for (int o = 32; o; o >>= 1) lm = fmaxf(lm, __shfl_xor(lm, o, 64));
    if (lane == 0) sred[w] = lm;
    __syncthreads();
    float mx = fmaxf(fmaxf(sred[0], sred[1]), fmaxf(sred[2], sred[3]));
    float ls = 0.f;
    for (int i = tid; i < Qq; i += 256) ls += __expf(srow[i] - mx);
    for (int o = 32; o; o >>= 1) ls += __shfl_xor(ls, o, 64);
    if (lane == 0) sred[4 + w] = ls;
    __syncthreads();
    float rz = 1.f / (sred[4] + sred[5] + sred[6] + sred[7]);
    for (int p = tid; p < QP; p += 256) {
      float v = (p < Qq) ? __expf(srow[p] - mx) * rz : 0.f;
      Ach[((m * NW + (p >> 6)) * KP + k) * 64 + (p & 63)] = f2bf(v);
    }
  } else {
    for (int p = tid; p < QP; p += 256)
      Ach[((m * NW + (p >> 6)) * KP + k) * 64 + (p & 63)] = 0;
  }
}

// softmax rows of B_logits -> bf16 BmT[m][j][cc<64][d<32] (zeros padded)
__global__ void prep_BmT_k(const float* __restrict__ Blog, short* __restrict__ BmT) {
  int m = blockIdx.x / QP, q = blockIdx.x % QP;
  int lane = threadIdx.x;  // block of 64
  bool act = (q < Qq) && (lane < Dd);
  float x = act ? Blog[(m * Qq + q) * Dd + lane] : -3.4e38f;
  float mm = x;
  for (int o = 32; o; o >>= 1) mm = fmaxf(mm, __shfl_xor(mm, o, 64));
  float e = act ? __expf(x - mm) : 0.f;
  float s = e;
  for (int o = 32; o; o >>= 1) s += __shfl_xor(s, o, 64);
  if (lane < 32) {
    float v = act ? (e / s) : 0.f;
    BmT[((m * NW + (q >> 6)) * 64 + (q & 63)) * 32 + lane] = f2bf(v);
  }
}

// softmax init_logits -> pi f32 [M][576] (zeros padded)
__global__ void prep_pi_k(const float* __restrict__ Ilog, float* __restrict__ pi) {
  __shared__ float srow[Qq];
  __shared__ float sred[8];
  int m = blockIdx.x;
  int tid = threadIdx.x; int lane = tid & 63; int w = tid >> 6;
  const float* rp = Ilog + m * Qq;
  for (int i = tid; i < Qq; i += 256) srow[i] = rp[i];
  __syncthreads();
  float lm = -3.4e38f;
  for (int i = tid; i < Qq; i += 256) lm = fmaxf(lm, srow[i]);
  for (int o = 32; o; o >>= 1) lm = fmaxf(lm, __shfl_xor(lm, o, 64));
  if (lane == 0) sred[w] = lm;
  __syncthreads();
  float mx = fmaxf(fmaxf(sred[0], sred[1]), fmaxf(sred[2], sred[3]));
  float ls = 0.f;
  for (int i = tid; i < Qq; i += 256) ls += __expf(srow[i] - mx);
  for (int o = 32; o; o >>= 1) ls += __shfl_xor(ls, o, 64);
  if (lane == 0) sred[4 + w] = ls;
  __syncthreads();
  float rz = 1.f / (sred[4] + sred[5] + sred[6] + sred[7]);
  for (int p = tid; p < QP; p += 256)
    pi[m * QP + p] = (p < Qq) ? __expf(srow[p] - mx) * rz : 0.f;
}

// ---------------- persistent scan kernel ----------------

__global__ void __launch_bounds__(256, 1) scan_k(
    const short* __restrict__ Ach, const short* __restrict__ obsb,
    const short* __restrict__ BmT, const float* __restrict__ pi,
    unsigned short* u16, float* ps, int* flag, float* __restrict__ out) {
  extern __shared__ char lds[];
  short* Alds = (short*)lds;                                 // [64][AST] A slice, transposed
  short* alds = (short*)(lds + 64 * AST * 2);                // [16][AST] alpha bf16
  short* blds = (short*)(lds + 80 * AST * 2);                // [64][32]  Bm^T slice
  float* sS   = (float*)(lds + 80 * AST * 2 + 4096);         // [16] row sums S
  float* red  = (float*)(lds + 80 * AST * 2 + 4096 + 64);    // [4][16] wave row partials
  short* tr   = (short*)(lds + 80 * AST * 2 + 4096 + 64 + 256);  // [16][68] uv transpose

  const int blk = blockIdx.x;
  const int c = blk & (NCL - 1);
  const int j = blk >> 3;
  const int m = c >> 2, bg = c & 3, b0 = bg * BCH;
  const int q0 = j * 64;
  const int tid = threadIdx.x, lane = tid & 63, w = tid >> 6;
  const int col = lane & 15, g = lane >> 4;
  const int qg = q0 + w * 16 + col;

  // one-time: A slice -> LDS transposed [cc][k]; Bm^T slice -> LDS
  for (int i = tid; i < KP * 64; i += 256) {
    int k = i >> 6, cc = i & 63;
    Alds[cc * AST + k] = Ach[((m * NW + j) * KP + k) * 64 + cc];
  }
  for (int i = tid; i < 64 * 32; i += 256) blds[i] = BmT[(m * NW + j) * 2048 + i];
  __syncthreads();

  const short* obsp = obsb + ((size_t)(m * Bb + b0 + col) * Tt) * 32 + g * 8;
  const short8 bmF = *(const short8*)(blds + (w * 16 + col) * 32 + g * 8);
  const f32x4 zf = {0.f, 0.f, 0.f, 0.f};
  float LL[4] = {0.f, 0.f, 0.f, 0.f};

  int* flagp = flag + c * 16 + (lane < NW ? lane : 0);
  unsigned short* ub0 = u16 + c * (BCH * QP);
  unsigned short* ub1 = u16 + (NCL + c) * (BCH * QP);

  for (int t = 0; t < Tt; ++t) {
    // E_t slice = obs_t @ Bm^T — issued before poll so load latency overlaps wait
    short8 obsF = *(const short8*)(obsp + t * 32);
    f32x4 eacc = __builtin_amdgcn_mfma_f32_16x16x32_bf16(obsF, bmF, zf, 0, 0, 0);

    float uvv[4];
    if (t == 0) {
      float piv = pi[m * QP + qg];
#pragma unroll
      for (int i = 0; i < 4; ++i) uvv[i] = eacc[i] * piv;
    } else {
      const int pp = (t - 1) & 1;
      // poll producers' flags for step t-1 (flag value = step+1, zero/poison safe)
      while (!__all(__hip_atomic_load(flagp, __ATOMIC_RELAXED, __HIP_MEMORY_SCOPE_AGENT) >= t)) {}
      __builtin_amdgcn_fence(__ATOMIC_ACQUIRE, "agent");
      // gather S partials (last 16 threads), overlapped with staging below
      if (tid >= 240) {
        int r = tid - 240; float s = 0.f;
#pragma unroll
        for (int q = 0; q < NW; ++q)
          s += __hip_atomic_load(ps + ((pp * NCL + c) * NW + q) * 16 + r,
                                 __ATOMIC_RELAXED, __HIP_MEMORY_SCOPE_AGENT);
        sS[r] = s;
      }
      // stage u_{t-1} bf16 [16][544] -> alds (8B agent loads, coalesced)
      const unsigned short* ubr = pp ? ub1 : ub0;
#pragma unroll
      for (int it = 0; it < 9; ++it) {
        int x = tid + it * 256;
        if (x < 2176) {  // 16 rows x 136 8B-chunks
          int r = x / 136, c4 = x - r * 136;
          unsigned long long v = __hip_atomic_load(
              (const unsigned long long*)(ubr + r * QP + c4 * 4),
              __ATOMIC_RELAXED, __HIP_MEMORY_SCOPE_AGENT);
          *(unsigned long long*)(alds + r * AST + c4 * 4) = v;
        }
      }
      __syncthreads();

      float rcp[4];
#pragma unroll
      for (int i = 0; i < 4; ++i) {
        float s = sS[g * 4 + i];
        rcp[i] = 1.f / s;
        LL[i] += __logf(s);
      }

      // R = alpha @ A_slice  (16 x 544 @ 544 x 16-per-wave)
      f32x4 acc = zf;
      const short* arow = alds + col * AST + g * 8;
      const short* brow = Alds + (w * 16 + col) * AST + g * 8;
#pragma unroll
      for (int kk = 0; kk < 17; ++kk) {
        short8 aF = *(const short8*)(arow + kk * 32);
        short8 bF = *(const short8*)(brow + kk * 32);
        acc = __builtin_amdgcn_mfma_f32_16x16x32_bf16(aF, bF, acc, 0, 0, 0);
      }
#pragma unroll
      for (int i = 0; i < 4; ++i) uvv[i] = eacc[i] * acc[i] * rcp[i];
    }

    if (t < Tt - 1) {
      const int p = t & 1;
      unsigned short* ubw = p ? ub1 : ub0;
      // row-sum partial over this wg's 64 cols + bf16 transpose for coalesced store
#pragma unroll
      for (int i = 0; i < 4; ++i) {
        float v = uvv[i];
        v += __shfl_xor(v, 1, 64); v += __shfl_xor(v, 2, 64);
        v += __shfl_xor(v, 4, 64); v += __shfl_xor(v, 8, 64);
        if (col == 0) red[w * 16 + g * 4 + i] = v;
        tr[(g * 4 + i) * 68 + w * 16 + col] = f2bf(uvv[i]);
      }
      __syncthreads();
      if (tid < 16) {
        float s = red[tid] + red[16 + tid] + red[32 + tid] + red[48 + tid];
        __hip_atomic_store(ps + ((p * NCL + c) * NW + j) * 16 + tid, s,
                           __ATOMIC_RELAXED, __HIP_MEMORY_SCOPE_AGENT);
      }
      {
        int r = tid >> 4, idx = tid & 15;
        unsigned long long v = *(const unsigned long long*)(tr + r * 68 + idx * 4);
        __hip_atomic_store((unsigned long long*)(ubw + r * QP + q0 + idx * 4), v,
                           __ATOMIC_RELAXED, __HIP_MEMORY_SCOPE_AGENT);
      }
      __syncthreads();  // drains every thread's stores (vmcnt(0)) before flag
      if (tid == 0)
        __hip_atomic_store(flag + c * 16 + j, t + 1, __ATOMIC_RELEASE, __HIP_MEMORY_SCOPE_AGENT);
    }

    // out write after the flag — off the inter-wg critical path
#pragma unroll
    for (int i = 0; i < 4; ++i) {
      if (qg < Qq)
        out[(((size_t)t * Mm + m) * Bb + b0 + g * 4 + i) * Qq + qg] = __logf(uvv[i]) + LL[i];
    }
  }
}

// ---------------- launch ----------------

extern "C" void kernel_launch(void* const* d_in, const int* in_sizes, int n_in,
                              void* d_out, int out_size, void* d_ws, size_t ws_size,
                              hipStream_t stream) {
  const float* obs  = (const float*)d_in[0];
  const float* Alog = (const float*)d_in[1];
  const float* Blog = (const float*)d_in[2];
  const float* Ilog = (const float*)d_in[3];
  float* out = (float*)d_out;
  char* ws = (char*)d_ws;

  // workspace layout (bytes)
  short*          Ach  = (short*)(ws + 0);              // 2*9*544*64*2   = 1,253,376
  short*          obsb = (short*)(ws + 1253376);        // 2*64*512*32*2  = 4,194,304
  short*          BmT  = (short*)(ws + 5447680);        // 2*9*64*32*2    = 73,728
  float*          pi   = (float*)(ws + 5521408);        // 2*576*4        = 4,608
  unsigned short* u16  = (unsigned short*)(ws + 5526016); // 2*8*16*576*2 = 294,912
  float*          ps   = (float*)(ws + 5820928);        // 2*8*9*16*4     = 9,216
  int*            flag = (int*)(ws + 5830144);          // 8*16*4         = 512
  if (ws_size < 5830656) return;

  hipMemsetAsync(flag, 0, 512, stream);
  prep_obs_k<<<(Mm * Bb * Tt * 32) / 256, 256, 0, stream>>>(obs, obsb);
  prep_A_k<<<Mm * KP, 256, 0, stream>>>(Alog, Ach);
  prep_BmT_k<<<Mm * QP, 64, 0, stream>>>(Blog, BmT);
  prep_pi_k<<<Mm, 256, 0, stream>>>(Ilog, pi);

  const int ldsBytes = 80 * AST * 2 + 4096 + 64 + 256 + 16 * 68 * 2;  // 97,472
  hipFuncSetAttribute((const void*)scan_k, hipFuncAttributeMaxDynamicSharedMemorySize, ldsBytes);
  scan_k<<<NBLK, 256, ldsBytes, stream>>>(Ach, obsb, BmT, pi, u16, ps, flag, out);
}

// Round 3
// 3521.313 us; speedup vs baseline: 1.1346x; 1.0559x over previous
//
#include <hip/hip_runtime.h>
#include <hip/hip_bf16.h>

// MsaHmmCell forward scan, MI355X tagged-payload design (R3).
// M=2, B=64, T=512, D=26, q=515. out[t,m,b,q] = log(u_t) + ll_{t-1}.
// 8 clusters (m x b-group-of-16) x 9 wgs (64-col slice of A each) = 72 wgs.
// Exchange: u words are f32 with low 9 mantissa bits = step tag (t+1).
// Consumers poll the data words directly (relaxed sc1) — no flags, no fences:
// validity and payload arrive in the same word. S is recomputed locally from
// the staged row (identical bits in every wg -> consistent ll). Flow control:
// a wg reaches step t+1 only after consuming all peers' step-t slices, so
// overwriting the (t-1)-parity buffer is safe; tags are unique per step
// (1..511, poison 0xAA -> tag 170 never aliases a fresh slot).

#define Tt 512
#define Mm 2
#define Bb 64
#define Dd 26
#define Qq 515
#define QP 576   // padded q (9 x 64 col chunks)
#define KP 544   // padded K (17 x 32)
#define AST 568  // LDS row stride (elems); 1136B -> 2-way max bank aliasing on b128 reads
#define BCH 16   // b rows per cluster (full MFMA row dim)
#define NCL 8    // clusters = Mm * (Bb/BCH)
#define NW 9     // wgs per cluster
#define NBLK 72

typedef __attribute__((ext_vector_type(4))) float f32x4;
typedef __attribute__((ext_vector_type(8))) short short8;

__device__ __forceinline__ short f2bf(float f) {
  union { float f; unsigned u; } v; v.f = f;
  unsigned r = v.u + 0x7FFFu + ((v.u >> 16) & 1u);  // RNE
  return (short)(r >> 16);
}

// ---------------- prep kernels ----------------

// obs f32 [M][B][T][26] -> bf16 [M][B][T][32] (d padded with 0)
__global__ void prep_obs_k(const float* __restrict__ obs, short* __restrict__ obsb) {
  int o = blockIdx.x * 256 + threadIdx.x;
  int d = o & 31; int r = o >> 5;
  float v = (d < Dd) ? obs[r * Dd + d] : 0.f;
  obsb[o] = f2bf(v);
}

// softmax rows of A_logits -> bf16 chunks Ach[m][j][k<544][cc<64] (zeros padded)
__global__ void prep_A_k(const float* __restrict__ Alog, short* __restrict__ Ach) {
  __shared__ float srow[Qq];
  __shared__ float sred[8];
  int m = blockIdx.x / KP, k = blockIdx.x % KP;
  int tid = threadIdx.x; int lane = tid & 63; int w = tid >> 6;
  if (k < Qq) {
    const float* rp = Alog + (m * Qq + k) * Qq;
    for (int i = tid; i < Qq; i += 256) srow[i] = rp[i];
    __syncthreads();
    float lm = -3.4e38f;
    for (int i = tid; i < Qq; i += 256) lm = fmaxf(lm, srow[i]);
    for (int o = 32; o; o >>= 1) lm = fmaxf(lm, __shfl_xor(lm, o, 64));
    if (lane == 0) sred[w] = lm;
    __syncthreads();
    float mx = fmaxf(fmaxf(sred[0], sred[1]), fmaxf(sred[2], sred[3]));
    float ls = 0.f;
    for (int i = tid; i < Qq; i += 256) ls += __expf(srow[i] - mx);
    for (int o = 32; o; o >>= 1) ls += __shfl_xor(ls, o, 64);
    if (lane == 0) sred[4 + w] = ls;
    __syncthreads();
    float rz = 1.f / (sred[4] + sred[5] + sred[6] + sred[7]);
    for (int p = tid; p < QP; p += 256) {
      float v = (p < Qq) ? __expf(srow[p] - mx) * rz : 0.f;
      Ach[((m * NW + (p >> 6)) * KP + k) * 64 + (p & 63)] = f2bf(v);
    }
  } else {
    for (int p = tid; p < QP; p += 256)
      Ach[((m * NW + (p >> 6)) * KP + k) * 64 + (p & 63)] = 0;
  }
}

// softmax rows of B_logits -> bf16 BmT[m][j][cc<64][d<32] (zeros padded)
__global__ void prep_BmT_k(const float* __restrict__ Blog, short* __restrict__ BmT) {
  int m = blockIdx.x / QP, q = blockIdx.x % QP;
  int lane = threadIdx.x;  // block of 64
  bool act = (q < Qq) && (lane < Dd);
  float x = act ? Blog[(m * Qq + q) * Dd + lane] : -3.4e38f;
  float mm = x;
  for (int o = 32; o; o >>= 1) mm = fmaxf(mm, __shfl_xor(mm, o, 64));
  float e = act ? __expf(x - mm) : 0.f;
  float s = e;
  for (int o = 32; o; o >>= 1) s += __shfl_xor(s, o, 64);
  if (lane < 32) {
    float v = act ? (e / s) : 0.f;
    BmT[((m * NW + (q >> 6)) * 64 + (q & 63)) * 32 + lane] = f2bf(v);
  }
}

// softmax init_logits -> pi f32 [M][576] (zeros padded)
__global__ void prep_pi_k(const float* __restrict__ Ilog, float* __restrict__ pi) {
  __shared__ float srow[Qq];
  __shared__ float sred[8];
  int m = blockIdx.x;
  int tid = threadIdx.x; int lane = tid & 63; int w = tid >> 6;
  const float* rp = Ilog + m * Qq;
  for (int i = tid; i < Qq; i += 256) srow[i] = rp[i];
  __syncthreads();
  float lm = -3.4e38f;
  for (int i = tid; i < Qq; i += 256) lm = fmaxf(lm, srow[i]);
  for (int o = 32; o; o >>= 1) lm = fmaxf(lm, __shfl_xor(lm, o, 64));
  if (lane == 0) sred[w] = lm;
  __syncthreads();
  float mx = fmaxf(fmaxf(sred[0], sred[1]), fmaxf(sred[2], sred[3]));
  float ls = 0.f;
  for (int i = tid; i < Qq; i += 256) ls += __expf(srow[i] - mx);
  for (int o = 32; o; o >>= 1) ls += __shfl_xor(ls, o, 64);
  if (lane == 0) sred[4 + w] = ls;
  __syncthreads();
  float rz = 1.f / (sred[4] + sred[5] + sred[6] + sred[7]);
  for (int p = tid; p < QP; p += 256)
    pi[m * QP + p] = (p < Qq) ? __expf(srow[p] - mx) * rz : 0.f;
}

// ---------------- persistent scan kernel ----------------

__global__ void __launch_bounds__(256, 1) scan_k(
    const short* __restrict__ Ach, const short* __restrict__ obsb,
    const short* __restrict__ BmT, const float* __restrict__ pi,
    unsigned* u, float* __restrict__ out) {
  extern __shared__ char lds[];
  short* Alds = (short*)lds;                          // [64][AST] A slice, transposed
  short* alds = (short*)(lds + 64 * AST * 2);         // [16][AST] alpha bf16
  short* blds = (short*)(lds + 80 * AST * 2);         // [64][32]  Bm^T slice
  float* sS   = (float*)(lds + 80 * AST * 2 + 4096);  // [16] row sums S

  const int blk = blockIdx.x;
  const int c = blk & (NCL - 1);
  const int j = blk >> 3;
  const int m = c >> 2, bg = c & 3, b0 = bg * BCH;
  const int q0 = j * 64;
  const int tid = threadIdx.x, lane = tid & 63, w = tid >> 6;
  const int col = lane & 15, g = lane >> 4;
  const int qg = q0 + w * 16 + col;

  // one-time: A slice -> LDS transposed [cc][k]; Bm^T slice -> LDS
  for (int i = tid; i < KP * 64; i += 256) {
    int k = i >> 6, cc = i & 63;
    Alds[cc * AST + k] = Ach[((m * NW + j) * KP + k) * 64 + cc];
  }
  for (int i = tid; i < 64 * 32; i += 256) blds[i] = BmT[(m * NW + j) * 2048 + i];
  __syncthreads();

  const short* obsp = obsb + ((size_t)(m * Bb + b0 + col) * Tt) * 32 + g * 8;
  const short8 bmF = *(const short8*)(blds + (w * 16 + col) * 32 + g * 8);
  const f32x4 zf = {0.f, 0.f, 0.f, 0.f};
  float LL[4] = {0.f, 0.f, 0.f, 0.f};

  unsigned* ub0 = u + c * (BCH * QP);
  unsigned* ub1 = u + (NCL + c) * (BCH * QP);

  // poll mapping: thread (r = tid>>4, c16 = tid&15) owns row r cols [c16*34, +34)
  const int pr = tid >> 4, pc = tid & 15;

  for (int t = 0; t < Tt; ++t) {
    // E_t slice = obs_t @ Bm^T — issued first so obs load latency overlaps poll
    short8 obsF = *(const short8*)(obsp + t * 32);
    f32x4 eacc = __builtin_amdgcn_mfma_f32_16x16x32_bf16(obsF, bmF, zf, 0, 0, 0);

    float uvv[4];
    if (t == 0) {
      float piv = pi[m * QP + qg];
#pragma unroll
      for (int i = 0; i < 4; ++i) uvv[i] = eacc[i] * piv;
    } else {
      // ---- poll u_{t-1}: data words carry tag t in low 9 bits ----
      const unsigned* ubr = ((t - 1) & 1 ? ub1 : ub0) + pr * QP + pc * 34;
      const unsigned tag = (unsigned)t;
      unsigned vals[34];
      bool done = false;
      while (!done) {
        bool ok = true;
#pragma unroll
        for (int i = 0; i < 34; ++i) {
          vals[i] = __hip_atomic_load(ubr + i, __ATOMIC_RELAXED, __HIP_MEMORY_SCOPE_AGENT);
          ok &= ((vals[i] & 511u) == tag);
        }
        done = ok;
      }
      // local row-sum S_r (identical bits & order in every wg of the cluster)
      float s = 0.f;
#pragma unroll
      for (int i = 0; i < 34; ++i) {
        union { unsigned u; float f; } cv; cv.u = vals[i];
        s += cv.f;
      }
      s += __shfl_xor(s, 1, 64); s += __shfl_xor(s, 2, 64);
      s += __shfl_xor(s, 4, 64); s += __shfl_xor(s, 8, 64);
      if (pc == 0) sS[pr] = s;
      // stage to LDS as bf16 (truncate: high 16 bits)
#pragma unroll
      for (int i = 0; i < 17; ++i) {
        unsigned pk = (vals[2 * i] >> 16) | (vals[2 * i + 1] & 0xFFFF0000u);
        *(unsigned*)(alds + pr * AST + pc * 34 + 2 * i) = pk;
      }
      __syncthreads();

      float rcp[4];
#pragma unroll
      for (int i = 0; i < 4; ++i) {
        float sv = sS[g * 4 + i];
        rcp[i] = 1.f / sv;
        LL[i] += __logf(sv);
      }

      // R = alpha @ A_slice  (16 x 544 @ 544 x 16-per-wave)
      f32x4 acc = zf;
      const short* arow = alds + col * AST + g * 8;
      const short* brow = Alds + (w * 16 + col) * AST + g * 8;
#pragma unroll
      for (int kk = 0; kk < 17; ++kk) {
        short8 aF = *(const short8*)(arow + kk * 32);
        short8 bF = *(const short8*)(brow + kk * 32);
        acc = __builtin_amdgcn_mfma_f32_16x16x32_bf16(aF, bF, acc, 0, 0, 0);
      }
#pragma unroll
      for (int i = 0; i < 4; ++i) uvv[i] = eacc[i] * acc[i] * rcp[i];
      __syncthreads();  // alds reads done before next step's staging overwrites
    }

    if (t < Tt - 1) {
      // publish u_t: f32 with low 9 mantissa bits = t+1 (fire-and-forget)
      unsigned* ubw = (t & 1 ? ub1 : ub0);
      const unsigned wtag = (unsigned)(t + 1);
#pragma unroll
      for (int i = 0; i < 4; ++i) {
        union { float f; unsigned u; } cv; cv.f = uvv[i];
        unsigned wv = (cv.u & ~511u) | wtag;
        __hip_atomic_store(ubw + (g * 4 + i) * QP + qg, wv,
                           __ATOMIC_RELAXED, __HIP_MEMORY_SCOPE_AGENT);
      }
    }

    // out write after publish — off the inter-wg critical path
#pragma unroll
    for (int i = 0; i < 4; ++i) {
      if (qg < Qq)
        out[(((size_t)t * Mm + m) * Bb + b0 + g * 4 + i) * Qq + qg] = __logf(uvv[i]) + LL[i];
    }
  }
}

// ---------------- launch ----------------

extern "C" void kernel_launch(void* const* d_in, const int* in_sizes, int n_in,
                              void* d_out, int out_size, void* d_ws, size_t ws_size,
                              hipStream_t stream) {
  const float* obs  = (const float*)d_in[0];
  const float* Alog = (const float*)d_in[1];
  const float* Blog = (const float*)d_in[2];
  const float* Ilog = (const float*)d_in[3];
  float* out = (float*)d_out;
  char* ws = (char*)d_ws;

  // workspace layout (bytes)
  short*    Ach  = (short*)(ws + 0);            // 2*9*544*64*2   = 1,253,376
  short*    obsb = (short*)(ws + 1253376);      // 2*64*512*32*2  = 4,194,304
  short*    BmT  = (short*)(ws + 5447680);      // 2*9*64*32*2    = 73,728
  float*    pi   = (float*)(ws + 5521408);      // 2*576*4        = 4,608
  unsigned* u    = (unsigned*)(ws + 5526016);   // 2*8*16*576*4   = 589,824
  if (ws_size < 6115840) return;

  prep_obs_k<<<(Mm * Bb * Tt * 32) / 256, 256, 0, stream>>>(obs, obsb);
  prep_A_k<<<Mm * KP, 256, 0, stream>>>(Alog, Ach);
  prep_BmT_k<<<Mm * QP, 64, 0, stream>>>(Blog, BmT);
  prep_pi_k<<<Mm, 256, 0, stream>>>(Ilog, pi);

  const int ldsBytes = 80 * AST * 2 + 4096 + 64 + 64;  // 95,008
  hipFuncSetAttribute((const void*)scan_k, hipFuncAttributeMaxDynamicSharedMemorySize, ldsBytes);
  scan_k<<<NBLK, 256, ldsBytes, stream>>>(Ach, obsb, BmT, pi, u, out);
}

// Round 4
// 1349.477 us; speedup vs baseline: 2.9606x; 2.6094x over previous
//
#include <hip/hip_runtime.h>
#include <hip/hip_bf16.h>

// MsaHmmCell forward scan, MI355X tagged-payload design, coalesced poll (R4).
// M=2, B=64, T=512, D=26, q=515. out[t,m,b,q] = log(u_t) + ll_{t-1}.
// 8 clusters (m x b-group-of-16) x 9 wgs (64-col slice of A each) = 72 wgs.
// Exchange: u words are f32 with low 9 mantissa bits = step tag (t+1).
// Consumers poll the data words directly via coalesced dwordx4 sc0 sc1 loads
// (16B/lane): validity and payload travel in the same word, so wide/torn
// loads are safe. No flags, no fences. S is recomputed locally from the
// polled registers in a fixed order (bitwise-identical in every wg of the
// cluster -> consistent ll). Flow control: a wg reaches step t+1 only after
// consuming all peers' step-t slices, so the 2-deep parity buffer is safe;
// tags are unique per step (1..511; 0xAA poison -> tag 170 never aliases
// because every word is rewritten from step 0 on).

#define Tt 512
#define Mm 2
#define Bb 64
#define Dd 26
#define Qq 515
#define QP 576    // padded q (9 x 64 col chunks)
#define KP 544    // padded K (17 x 32)
#define ASTA 552  // LDS row stride (bf16 elems) for A slice (69 16B-slots, odd)
#define ASTL 584  // LDS row stride (bf16 elems) for alpha (73 16B-slots, odd)
#define BCH 16    // b rows per cluster (full MFMA row dim)
#define NCL 8     // clusters = Mm * (Bb/BCH)
#define NW 9      // wgs per cluster
#define NBLK 72

typedef __attribute__((ext_vector_type(4))) float f32x4;
typedef __attribute__((ext_vector_type(8))) short short8;
typedef __attribute__((ext_vector_type(4))) unsigned uint4v;

__device__ __forceinline__ short f2bf(float f) {
  union { float f; unsigned u; } v; v.f = f;
  unsigned r = v.u + 0x7FFFu + ((v.u >> 16) & 1u);  // RNE
  return (short)(r >> 16);
}

// 9 coherent 16B loads (one per producer wg), batched: all in flight, one wait.
__device__ __forceinline__ void load9(const unsigned* base, uint4v* v) {
  asm volatile(
      "global_load_dwordx4 %0, %[a], off sc0 sc1\n\t"
      "global_load_dwordx4 %1, %[a], off offset:256 sc0 sc1\n\t"
      "global_load_dwordx4 %2, %[a], off offset:512 sc0 sc1\n\t"
      "global_load_dwordx4 %3, %[a], off offset:768 sc0 sc1\n\t"
      "global_load_dwordx4 %4, %[a], off offset:1024 sc0 sc1\n\t"
      "global_load_dwordx4 %5, %[a], off offset:1280 sc0 sc1\n\t"
      "global_load_dwordx4 %6, %[a], off offset:1536 sc0 sc1\n\t"
      "global_load_dwordx4 %7, %[a], off offset:1792 sc0 sc1\n\t"
      "global_load_dwordx4 %8, %[a], off offset:2048 sc0 sc1\n\t"
      "s_waitcnt vmcnt(0)"
      : "=v"(v[0]), "=v"(v[1]), "=v"(v[2]), "=v"(v[3]), "=v"(v[4]),
        "=v"(v[5]), "=v"(v[6]), "=v"(v[7]), "=v"(v[8])
      : [a] "v"(base)
      : "memory");
}

// ---------------- prep kernels ----------------

// obs f32 [M][B][T][26] -> bf16 [M][B][T][32] (d padded with 0)
__global__ void prep_obs_k(const float* __restrict__ obs, short* __restrict__ obsb) {
  int o = blockIdx.x * 256 + threadIdx.x;
  int d = o & 31; int r = o >> 5;
  float v = (d < Dd) ? obs[r * Dd + d] : 0.f;
  obsb[o] = f2bf(v);
}

// softmax rows of A_logits -> bf16 chunks Ach[m][j][k<544][cc<64] (zeros padded)
__global__ void prep_A_k(const float* __restrict__ Alog, short* __restrict__ Ach) {
  __shared__ float srow[Qq];
  __shared__ float sred[8];
  int m = blockIdx.x / KP, k = blockIdx.x % KP;
  int tid = threadIdx.x; int lane = tid & 63; int w = tid >> 6;
  if (k < Qq) {
    const float* rp = Alog + (m * Qq + k) * Qq;
    for (int i = tid; i < Qq; i += 256) srow[i] = rp[i];
    __syncthreads();
    float lm = -3.4e38f;
    for (int i = tid; i < Qq; i += 256) lm = fmaxf(lm, srow[i]);
    for (int o = 32; o; o >>= 1) lm = fmaxf(lm, __shfl_xor(lm, o, 64));
    if (lane == 0) sred[w] = lm;
    __syncthreads();
    float mx = fmaxf(fmaxf(sred[0], sred[1]), fmaxf(sred[2], sred[3]));
    float ls = 0.f;
    for (int i = tid; i < Qq; i += 256) ls += __expf(srow[i] - mx);
    for (int o = 32; o; o >>= 1) ls += __shfl_xor(ls, o, 64);
    if (lane == 0) sred[4 + w] = ls;
    __syncthreads();
    float rz = 1.f / (sred[4] + sred[5] + sred[6] + sred[7]);
    for (int p = tid; p < QP; p += 256) {
      float v = (p < Qq) ? __expf(srow[p] - mx) * rz : 0.f;
      Ach[((m * NW + (p >> 6)) * KP + k) * 64 + (p & 63)] = f2bf(v);
    }
  } else {
    for (int p = tid; p < QP; p += 256)
      Ach[((m * NW + (p >> 6)) * KP + k) * 64 + (p & 63)] = 0;
  }
}

// softmax rows of B_logits -> bf16 BmT[m][j][cc<64][d<32] (zeros padded)
__global__ void prep_BmT_k(const float* __restrict__ Blog, short* __restrict__ BmT) {
  int m = blockIdx.x / QP, q = blockIdx.x % QP;
  int lane = threadIdx.x;  // block of 64
  bool act = (q < Qq) && (lane < Dd);
  float x = act ? Blog[(m * Qq + q) * Dd + lane] : -3.4e38f;
  float mm = x;
  for (int o = 32; o; o >>= 1) mm = fmaxf(mm, __shfl_xor(mm, o, 64));
  float e = act ? __expf(x - mm) : 0.f;
  float s = e;
  for (int o = 32; o; o >>= 1) s += __shfl_xor(s, o, 64);
  if (lane < 32) {
    float v = act ? (e / s) : 0.f;
    BmT[((m * NW + (q >> 6)) * 64 + (q & 63)) * 32 + lane] = f2bf(v);
  }
}

// softmax init_logits -> pi f32 [M][576] (zeros padded)
__global__ void prep_pi_k(const float* __restrict__ Ilog, float* __restrict__ pi) {
  __shared__ float srow[Qq];
  __shared__ float sred[8];
  int m = blockIdx.x;
  int tid = threadIdx.x; int lane = tid & 63; int w = tid >> 6;
  const float* rp = Ilog + m * Qq;
  for (int i = tid; i < Qq; i += 256) srow[i] = rp[i];
  __syncthreads();
  float lm = -3.4e38f;
  for (int i = tid; i < Qq; i += 256) lm = fmaxf(lm, srow[i]);
  for (int o = 32; o; o >>= 1) lm = fmaxf(lm, __shfl_xor(lm, o, 64));
  if (lane == 0) sred[w] = lm;
  __syncthreads();
  float mx = fmaxf(fmaxf(sred[0], sred[1]), fmaxf(sred[2], sred[3]));
  float ls = 0.f;
  for (int i = tid; i < Qq; i += 256) ls += __expf(srow[i] - mx);
  for (int o = 32; o; o >>= 1) ls += __shfl_xor(ls, o, 64);
  if (lane == 0) sred[4 + w] = ls;
  __syncthreads();
  float rz = 1.f / (sred[4] + sred[5] + sred[6] + sred[7]);
  for (int p = tid; p < QP; p += 256)
    pi[m * QP + p] = (p < Qq) ? __expf(srow[p] - mx) * rz : 0.f;
}

// ---------------- persistent scan kernel ----------------

__global__ void __launch_bounds__(256, 1) scan_k(
    const short* __restrict__ Ach, const short* __restrict__ obsb,
    const short* __restrict__ BmT, const float* __restrict__ pi,
    unsigned* u, float* __restrict__ out) {
  extern __shared__ char lds[];
  short* Alds = (short*)lds;                            // [64][ASTA] A slice, transposed
  short* alds = (short*)(lds + 64 * ASTA * 2);          // [16][ASTL] alpha bf16
  short* blds = (short*)(lds + 64 * ASTA * 2 + 16 * ASTL * 2);  // [64][32] Bm^T slice
  float* sS   = (float*)(lds + 64 * ASTA * 2 + 16 * ASTL * 2 + 4096);  // [16] row sums

  const int blk = blockIdx.x;
  const int c = blk & (NCL - 1);   // cluster; members == mod 8 -> same XCD
  const int j = blk >> 3;          // col-chunk 0..8
  const int m = c >> 2, bg = c & 3, b0 = bg * BCH;
  const int q0 = j * 64;
  const int tid = threadIdx.x, lane = tid & 63, w = tid >> 6;
  const int col = lane & 15, g = lane >> 4;
  const int qg = q0 + w * 16 + col;

  // one-time: A slice -> LDS transposed [cc][k]; Bm^T slice -> LDS
  for (int i = tid; i < KP * 64; i += 256) {
    int k = i >> 6, cc = i & 63;
    Alds[cc * ASTA + k] = Ach[((m * NW + j) * KP + k) * 64 + cc];
  }
  for (int i = tid; i < 64 * 32; i += 256) blds[i] = BmT[(m * NW + j) * 2048 + i];
  __syncthreads();

  const short* obsp = obsb + ((size_t)(m * Bb + b0 + col) * Tt) * 32 + g * 8;
  const short8 bmF = *(const short8*)(blds + (w * 16 + col) * 32 + g * 8);
  const f32x4 zf = {0.f, 0.f, 0.f, 0.f};
  float LL[4] = {0.f, 0.f, 0.f, 0.f};

  unsigned* ub0 = u + c * (BCH * QP);
  unsigned* ub1 = u + (NCL + c) * (BCH * QP);

  // poll mapping: thread (pr = tid>>4, pc = tid&15) owns row pr,
  // producer-k chunk = words [k*64 + pc*4, +4)  (16B, lane-contiguous)
  const int pr = tid >> 4, pc = tid & 15;

  for (int t = 0; t < Tt; ++t) {
    // E_t slice = obs_t @ Bm^T — issued first so obs load latency overlaps poll
    short8 obsF = *(const short8*)(obsp + t * 32);
    f32x4 eacc = __builtin_amdgcn_mfma_f32_16x16x32_bf16(obsF, bmF, zf, 0, 0, 0);

    float uvv[4];
    if (t == 0) {
      float piv = pi[m * QP + qg];
#pragma unroll
      for (int i = 0; i < 4; ++i) uvv[i] = eacc[i] * piv;
    } else {
      // ---- poll u_{t-1}: data words carry tag t in low 9 bits ----
      const unsigned* base = ((t - 1) & 1 ? ub1 : ub0) + pr * QP + pc * 4;
      const unsigned tag = (unsigned)t;
      uint4v v[9];
      unsigned ok;
      do {
        load9(base, v);
        ok = 1u;
#pragma unroll
        for (int k = 0; k < 9; ++k)
          ok &= ((v[k].x & 511u) == tag) & ((v[k].y & 511u) == tag) &
                ((v[k].z & 511u) == tag) & ((v[k].w & 511u) == tag);
      } while (!ok);

      // local row-sum S_pr (fixed order -> identical bits in every wg) and
      // bf16 staging of alpha to LDS (truncate: take high 16 bits)
      float s = 0.f;
#pragma unroll
      for (int k = 0; k < 9; ++k) {
        union { unsigned u; float f; } c0, c1, c2, c3;
        c0.u = v[k].x; c1.u = v[k].y; c2.u = v[k].z; c3.u = v[k].w;
        s += c0.f + c1.f + c2.f + c3.f;
        unsigned lo = (v[k].x >> 16) | (v[k].y & 0xFFFF0000u);
        unsigned hi = (v[k].z >> 16) | (v[k].w & 0xFFFF0000u);
        *(unsigned long long*)(alds + pr * ASTL + k * 64 + pc * 4) =
            (unsigned long long)lo | ((unsigned long long)hi << 32);
      }
      s += __shfl_xor(s, 1, 64); s += __shfl_xor(s, 2, 64);
      s += __shfl_xor(s, 4, 64); s += __shfl_xor(s, 8, 64);
      if (pc == 0) sS[pr] = s;
      __syncthreads();

      float rcp[4];
#pragma unroll
      for (int i = 0; i < 4; ++i) {
        float sv = sS[g * 4 + i];
        rcp[i] = 1.f / sv;
        LL[i] += __logf(sv);
      }

      // R = alpha @ A_slice (16 x 544 @ 544 x 16-per-wave), 2 indep chains
      f32x4 acc0 = zf, acc1 = zf;
      const short* arow = alds + col * ASTL + g * 8;
      const short* brow = Alds + (w * 16 + col) * ASTA + g * 8;
#pragma unroll
      for (int kk = 0; kk < 17; ++kk) {
        short8 aF = *(const short8*)(arow + kk * 32);
        short8 bF = *(const short8*)(brow + kk * 32);
        if (kk & 1) acc1 = __builtin_amdgcn_mfma_f32_16x16x32_bf16(aF, bF, acc1, 0, 0, 0);
        else        acc0 = __builtin_amdgcn_mfma_f32_16x16x32_bf16(aF, bF, acc0, 0, 0, 0);
      }
#pragma unroll
      for (int i = 0; i < 4; ++i) uvv[i] = eacc[i] * (acc0[i] + acc1[i]) * rcp[i];
      __syncthreads();  // alds reads done before next step's staging overwrites
    }

    if (t < Tt - 1) {
      // publish u_t: f32 with low 9 mantissa bits = t+1 (fire-and-forget)
      unsigned* ubw = (t & 1 ? ub1 : ub0);
      const unsigned wtag = (unsigned)(t + 1);
#pragma unroll
      for (int i = 0; i < 4; ++i) {
        union { float f; unsigned u; } cv; cv.f = uvv[i];
        unsigned wv = (cv.u & ~511u) | wtag;
        __hip_atomic_store(ubw + (g * 4 + i) * QP + qg, wv,
                           __ATOMIC_RELAXED, __HIP_MEMORY_SCOPE_AGENT);
      }
    }

    // out write after publish — off the inter-wg critical path
#pragma unroll
    for (int i = 0; i < 4; ++i) {
      if (qg < Qq)
        out[(((size_t)t * Mm + m) * Bb + b0 + g * 4 + i) * Qq + qg] = __logf(uvv[i]) + LL[i];
    }
  }
}

// ---------------- launch ----------------

extern "C" void kernel_launch(void* const* d_in, const int* in_sizes, int n_in,
                              void* d_out, int out_size, void* d_ws, size_t ws_size,
                              hipStream_t stream) {
  const float* obs  = (const float*)d_in[0];
  const float* Alog = (const float*)d_in[1];
  const float* Blog = (const float*)d_in[2];
  const float* Ilog = (const float*)d_in[3];
  float* out = (float*)d_out;
  char* ws = (char*)d_ws;

  // workspace layout (bytes)
  short*    Ach  = (short*)(ws + 0);            // 2*9*544*64*2   = 1,253,376
  short*    obsb = (short*)(ws + 1253376);      // 2*64*512*32*2  = 4,194,304
  short*    BmT  = (short*)(ws + 5447680);      // 2*9*64*32*2    = 73,728
  float*    pi   = (float*)(ws + 5521408);      // 2*576*4        = 4,608
  unsigned* u    = (unsigned*)(ws + 5526016);   // 2*8*16*576*4   = 589,824
  if (ws_size < 6115840) return;

  prep_obs_k<<<(Mm * Bb * Tt * 32) / 256, 256, 0, stream>>>(obs, obsb);
  prep_A_k<<<Mm * KP, 256, 0, stream>>>(Alog, Ach);
  prep_BmT_k<<<Mm * QP, 64, 0, stream>>>(Blog, BmT);
  prep_pi_k<<<Mm, 256, 0, stream>>>(Ilog, pi);

  const int ldsBytes = 64 * ASTA * 2 + 16 * ASTL * 2 + 4096 + 64;  // 93,504
  hipFuncSetAttribute((const void*)scan_k, hipFuncAttributeMaxDynamicSharedMemorySize, ldsBytes);
  scan_k<<<NBLK, 256, ldsBytes, stream>>>(Ach, obsb, BmT, pi, u, out);
}